// Round 5
// baseline (283.858 us; speedup 1.0000x reference)
//
#include <hip/hip_runtime.h>
#include <stdint.h>

typedef __bf16 bf16;
typedef bf16 bf16x4 __attribute__((ext_vector_type(4)));
typedef bf16 bf16x8 __attribute__((ext_vector_type(8)));
typedef float f32x4 __attribute__((ext_vector_type(4)));

// Inputs fp32, output fp32. Internal: bf16 MFMA, fp32 acc.
// Q is pre-scaled by 0.125*log2(e) in the QKV epilogue so attention softmax
// is exp2(s) with zero extra VALU per element.

// Async global->LDS, 16B/lane; LDS dest = wave-uniform base + lane*16 [m97].
__device__ __forceinline__ void gll16(const bf16* g, const bf16* l) {
  __builtin_amdgcn_global_load_lds(
      (__attribute__((address_space(1))) void*)(g),
      (__attribute__((address_space(3))) void*)(l),
      16, 0, 0);
}

// ---------------- LayerNorm: one block per row of 1024, fp32 in -> bf16 out ----------------
__global__ __launch_bounds__(256) void ln_kernel(
    const float* __restrict__ x, const float* __restrict__ gamma,
    const float* __restrict__ beta, bf16* __restrict__ xn)
{
  __shared__ float red[8];
  const long row = blockIdx.x;
  const int t = threadIdx.x;
  f32x4 f = *(const f32x4*)(x + row * 1024 + t * 4);
  float sum = f[0] + f[1] + f[2] + f[3];
  float sq  = f[0]*f[0] + f[1]*f[1] + f[2]*f[2] + f[3]*f[3];
#pragma unroll
  for (int sh = 1; sh < 64; sh <<= 1) {
    sum += __shfl_xor(sum, sh, 64);
    sq  += __shfl_xor(sq,  sh, 64);
  }
  const int wave = t >> 6, lane = t & 63;
  if (lane == 0) { red[wave] = sum; red[wave + 4] = sq; }
  __syncthreads();
  sum = red[0] + red[1] + red[2] + red[3];
  sq  = red[4] + red[5] + red[6] + red[7];
  const float mu  = sum * (1.0f / 1024.0f);
  const float var = sq * (1.0f / 1024.0f) - mu * mu;
  const float rs  = rsqrtf(var + 1e-5f);
  f32x4 g = *(const f32x4*)(gamma + t * 4);
  f32x4 bb = *(const f32x4*)(beta + t * 4);
  bf16x4 ov;
#pragma unroll
  for (int i = 0; i < 4; i++)
    ov[i] = (bf16)((f[i] - mu) * rs * g[i] + bb[i]);
  *(bf16x4*)(xn + row * 1024 + t * 4) = ov;
}

// ---------------- Weight transposes (both weights, one launch): out[c][r] = (bf16)in[r][c] ----------------
// blockIdx.x < 96: w_qkv (1024x3072); else w_out (1024x1024). R = 1024 for both.
__global__ __launch_bounds__(256) void transpose2_kernel(
    const float* __restrict__ wqkv, bf16* __restrict__ wqkvT,
    const float* __restrict__ wout, bf16* __restrict__ woutT)
{
  __shared__ bf16 tile[32][33];
  const int bx = blockIdx.x;
  const float* in;
  bf16* out;
  int Cc, c0;
  if (bx < 96) { in = wqkv; out = wqkvT; Cc = 3072; c0 = bx * 32; }
  else         { in = wout; out = woutT; Cc = 1024; c0 = (bx - 96) * 32; }
  const int r0 = blockIdx.y * 32;
  const int tx = threadIdx.x & 31, ty = threadIdx.x >> 5;
#pragma unroll
  for (int i = 0; i < 32; i += 8)
    tile[ty + i][tx] = (bf16)in[(long)(r0 + ty + i) * Cc + c0 + tx];
  __syncthreads();
#pragma unroll
  for (int i = 0; i < 32; i += 8)
    out[(long)(c0 + ty + i) * 1024 + r0 + tx] = tile[tx][ty + i];
}

// ---------------- GEMM: C[m][n] = sum_k A[m][k] * BT[n][k] + bias[n] ----------------
// 128x128 tile, BK=32, 4 waves each 64x64, global_load_lds x16.
// Depth-2 pipeline (T4, counted vmcnt): 3 LDS buffers rotate; stage(s+2) is
// issued at step s, then inline-asm s_waitcnt vmcnt(8) (allow stages s+1,s+2
// = 8 glls outstanding; retire stage s) + RAW s_barrier (no vmcnt(0) drain).
// Tail peels to vmcnt(4)/vmcnt(0). Hazards: buf[(s+2)%3]=buf[(s-1)%3], whose
// last reads finished before step s-1's closing barrier (precedes the issue).
// LDS bank-swizzle (rule #21: linear gll dest + pre-swizzled SOURCE + swizzled
// READ): 16B granule g of row r stores global granule g ^ ((r>>1)&3). Kills
// the 8-accesses-per-bank pattern of 64B rows (measured +4cyc per ds_read).
// Read key reduces to quad ^ ((c16>>1)&3) for all fragment rows.
// mode 0: store C [M][N] fp32. mode 1: QKV scatter bf16 (q/k [bh][l][64], v->vt [bh][64][l]);
//   Q is additionally scaled by 0.125*log2(e) for the exp2-softmax in attn.
__global__ __launch_bounds__(256, 3) void gemm_bt(
    const bf16* __restrict__ A, const bf16* __restrict__ BT,
    const float* __restrict__ bias, float* __restrict__ C,
    bf16* __restrict__ qb, bf16* __restrict__ kb, bf16* __restrict__ vtb,
    int K, int N, int mode)
{
  __shared__ bf16 sA[3][128 * 32];
  __shared__ bf16 sB[3][128 * 32];
  const int t = threadIdx.x;
  const int lane = t & 63;
  const int wave = t >> 6;
  const int wave_u = __builtin_amdgcn_readfirstlane(wave);
  const int quad = lane >> 4;
  const int c16 = lane & 15;
  const int wm = (wave >> 1) * 64;
  const int wn = (wave & 1) * 64;
  const int m0 = blockIdx.x * 128;
  const int n0 = blockIdx.y * 128;

  f32x4 acc[4][4] = {};

  const int srow = t >> 2;                               // 0..63
  const int scol = (((t & 3) ^ ((t >> 3) & 3)) * 8);     // pre-swizzled source granule
  const bf16* gA = A + (long)(m0 + srow) * K + scol;
  const bf16* gB = BT + (long)(n0 + srow) * K + scol;
  const long rowskip = (long)64 * K;
  const int ksw = (quad ^ ((c16 >> 1) & 3)) * 8;         // swizzled read offset (elems)

  const int S = K >> 5;                                  // number of 32-wide K-steps

  // stage K-step kk (global col kk*32) into buffer b
  auto stage = [&](int b, int kk) {
    const bf16* lA = sA[0] + b * 4096 + wave_u * 512;
    const bf16* lB = sB[0] + b * 4096 + wave_u * 512;
    const int k0 = kk * 32;
    gll16(gA + k0, lA);
    gll16(gA + k0 + rowskip, lA + 2048);
    gll16(gB + k0, lB);
    gll16(gB + k0 + rowskip, lB + 2048);
  };

  // prologue: stage steps 0 and 1 (K >= 64 always here)
  stage(0, 0);
  stage(1, 1);

  int bcur = 0;
  for (int s = 0; s < S; s++) {
    if (s + 2 < S) {
      const int bnx = (bcur >= 1) ? bcur - 1 : 2;        // (s+2) % 3
      stage(bnx, s + 2);
      asm volatile("s_waitcnt vmcnt(8)" ::: "memory");   // retire stage(s); keep s+1,s+2 in flight
    } else if (s + 1 < S) {
      asm volatile("s_waitcnt vmcnt(4)" ::: "memory");   // retire stage(s); keep s+1
    } else {
      asm volatile("s_waitcnt vmcnt(0)" ::: "memory");   // last step
    }
    __builtin_amdgcn_s_barrier();                        // all waves' stage(s) slices visible

    const bf16* cA = sA[0] + bcur * 4096;
    const bf16* cB = sB[0] + bcur * 4096;
    bf16x8 af[4], bfr[4];
#pragma unroll
    for (int i = 0; i < 4; i++)
      af[i] = *(const bf16x8*)(cA + (wm + i * 16 + c16) * 32 + ksw);
#pragma unroll
    for (int j = 0; j < 4; j++)
      bfr[j] = *(const bf16x8*)(cB + (wn + j * 16 + c16) * 32 + ksw);
#pragma unroll
    for (int i = 0; i < 4; i++)
#pragma unroll
      for (int j = 0; j < 4; j++)
        acc[i][j] = __builtin_amdgcn_mfma_f32_16x16x32_bf16(af[i], bfr[j], acc[i][j], 0, 0, 0);

    __builtin_amdgcn_s_barrier();                        // reads of buf[bcur] done before overwrite
    bcur = (bcur == 2) ? 0 : bcur + 1;
  }

  // C/D layout: col = lane&15, row = quad*4 + reg   [verified m89/m91]
#pragma unroll
  for (int i = 0; i < 4; i++) {
    const int mbase = m0 + wm + i * 16 + quad * 4;
#pragma unroll
    for (int j = 0; j < 4; j++) {
      const int n = n0 + wn + j * 16 + c16;
      const float bv = bias[n];
      if (mode == 0) {
#pragma unroll
        for (int r = 0; r < 4; r++)
          C[(long)(mbase + r) * N + n] = acc[i][j][r] + bv;
      } else {
        const int part = n >> 10;       // 0=Q 1=K 2=V
        const int inner = n & 1023;
        const int h = inner >> 6, d = inner & 63;
#pragma unroll
        for (int r = 0; r < 4; r++) {
          const int m = mbase + r;
          const int b = m >> 11, l = m & 2047;
          const long bh = (long)((b << 4) | h);
          const float v = acc[i][j][r] + bv;
          if (part == 0)      qb [(bh * 2048 + l) * 64 + d] = (bf16)(v * 0.18033688f); // 0.125*log2e
          else if (part == 1) kb [(bh * 2048 + l) * 64 + d] = (bf16)v;
          else                vtb[(bh * 64 + d) * 2048 + l] = (bf16)v;
        }
      }
    }
  }
}

// ---------------- Flash attention: swapped QK^T, P in registers ----------------
// LDS-staged K/V (round-1 lesson: direct-L2 operand reads are latency-bound).
//   * QK^T computed SWAPPED: z = mfma(K_frag, Q_frag) -> S^T[kv][q] with
//     q = lane column (c16). Each lane's P values all belong to one q-row,
//     so softmax P never goes through LDS (no extra barrier, no scalar stores).
//   * PV A-fragment slot k=quad*8+j wants kv=quad*8+j but the lane holds
//     kv=16e+4*quad+r. Fix: permute the kv axis by sigma(16e+4q+r)=8q+4e+r
//     on BOTH operands (contraction order is free): P packs lane-locally
//     with zero shuffles, and V^T is staged into LDS pre-permuted
//     (two b64 writes per staging lane instead of one b128).
// Per wave: 32 q-rows (2 m-tiles). Block: 4 waves = 128 q-rows. Grid:
// 16 q-tiles x 64 bh = 1024 blocks = exactly 4 blocks/CU, all co-resident.
// XCD-affine: i&7 = XCD [m157]; XCD x owns bh [8x,8x+8), sequential per bh,
// so K/V (512 KB/bh) stays in that XCD's 4 MB L2 across all 16 q-tiles.
// K and V both register-prefetched one 128-kv tile ahead (issued mid-compute).
// 2 barriers/iter. p_sum is a per-lane scalar; quad-reduce at the end.
__global__ __launch_bounds__(256, 4) void attn_kernel(
    const bf16* __restrict__ q, const bf16* __restrict__ k,
    const bf16* __restrict__ vt, bf16* __restrict__ att)
{
  __shared__ bf16 sK[128 * 68];      // [kv][d], stride 68 (34 words, mod32=2)
  __shared__ bf16 sVt[64 * 132];     // [d][kv-permuted], stride 132 (66 words, mod32=2)

  const int i = blockIdx.x;                 // 0..1023
  const int xcd = i & 7;
  const int wi = i >> 3;                    // 0..127
  const int qt = wi & 15;
  const int bh = xcd * 8 + (wi >> 4);
  const int b = bh >> 4, h = bh & 15;
  const int q0 = qt * 128;
  const int t = threadIdx.x;
  const int wave = t >> 6, lane = t & 63;
  const int quad = lane >> 4, c16 = lane & 15;

  const bf16* qp = q + (long)bh * (2048 * 64);
  const bf16* kp = k + (long)bh * (2048 * 64);
  const bf16* vp = vt + (long)bh * (64 * 2048);

  // Q fragments (B-operand now): B[q=c16][d=quad*8+..], loop-invariant
  bf16x8 aq[2][2];
#pragma unroll
  for (int m = 0; m < 2; m++) {
    const bf16* qrow = qp + (long)(q0 + wave * 32 + m * 16 + c16) * 64 + quad * 8;
    aq[m][0] = *(const bf16x8*)(qrow);
    aq[m][1] = *(const bf16x8*)(qrow + 32);
  }

  float p_sum[2] = {0.0f, 0.0f};
  f32x4 o_acc[2][4] = {};

  // staging indices
  const int kr = t >> 3;             // K row within 32-row group
  const int kd = (t & 7) * 8;
  const int vr = t >> 4;             // Vt row within 16-row group (0..15)
  const int vc = t & 15;             // 8-kv chunk index (0..15)
  const int vl = vc * 8;             // global kv offset
  // permuted LDS dest: chunk ks=vc>>2, cc=vc&3 -> D0 = ks*32 + 16*(cc&1) + 4*(cc>>1)
  const int vD0 = (vc >> 2) * 32 + (vc & 1) * 16 + ((vc >> 1) & 1) * 4;

  // prefetch tile 0 (K and V) into registers
  bf16x8 kreg[4], vreg[4];
#pragma unroll
  for (int it = 0; it < 4; it++) {
    kreg[it] = *(const bf16x8*)(kp + (long)(it * 32 + kr) * 64 + kd);
    vreg[it] = *(const bf16x8*)(vp + (long)(it * 16 + vr) * 2048 + vl);
  }

  for (int kt = 0; kt < 16; kt++) {
    __syncthreads();   // b1: prev iter's LDS reads done
#pragma unroll
    for (int it = 0; it < 4; it++)
      *(bf16x8*)&sK[(it * 32 + kr) * 68 + kd] = kreg[it];
#pragma unroll
    for (int it = 0; it < 4; it++) {
      const bf16x8 v = vreg[it];
      const bf16x4 lo = __builtin_shufflevector(v, v, 0, 1, 2, 3);
      const bf16x4 hi = __builtin_shufflevector(v, v, 4, 5, 6, 7);
      bf16* d = &sVt[(it * 16 + vr) * 132 + vD0];
      *(bf16x4*)(d)     = lo;   // kv 16e+4q+r with r=0..3  -> slots D0..D0+3
      *(bf16x4*)(d + 8) = hi;   // next q group              -> slots D0+8..D0+11
    }
    __syncthreads();   // b2: tiles visible

    const int kvn = ((kt + 1) & 15) * 128;

#pragma unroll
    for (int ks = 0; ks < 4; ks++) {
      bf16x8 ap[2];
      // QK^T (swapped) + exp2 + lane-local pack for this 32-kv chunk
#pragma unroll
      for (int e = 0; e < 2; e++) {
        const int jb = ks * 2 + e;
        const bf16x8 bk0 = *(const bf16x8*)&sK[(jb * 16 + c16) * 68 + quad * 8];
        const bf16x8 bk1 = *(const bf16x8*)&sK[(jb * 16 + c16) * 68 + 32 + quad * 8];
#pragma unroll
        for (int m = 0; m < 2; m++) {
          f32x4 z = {};
          z = __builtin_amdgcn_mfma_f32_16x16x32_bf16(bk0, aq[m][0], z, 0, 0, 0);
          z = __builtin_amdgcn_mfma_f32_16x16x32_bf16(bk1, aq[m][1], z, 0, 0, 0);
          // D: row = kv_local = quad*4+r, col = q = c16
#pragma unroll
          for (int r = 0; r < 4; r++) {
            const float p = __builtin_amdgcn_exp2f(z[r]);
            p_sum[m] += p;
            ap[m][e * 4 + r] = (bf16)p;   // slot sigma(kv): lane-local, no shuffle
          }
        }
      }
      // mid-compute prefetch of next tile (latency hidden under remaining MFMAs)
      if (ks == 1) {
#pragma unroll
        for (int it = 0; it < 4; it++)
          kreg[it] = *(const bf16x8*)(kp + (long)(kvn + it * 32 + kr) * 64 + kd);
      }
      if (ks == 2) {
#pragma unroll
        for (int it = 0; it < 4; it++)
          vreg[it] = *(const bf16x8*)(vp + (long)(it * 16 + vr) * 2048 + kvn + vl);
      }
      // O += P @ V over this 32-kv chunk (V^T pre-permuted: contiguous b128)
#pragma unroll
      for (int jd = 0; jd < 4; jd++) {
        const bf16x8 bv = *(const bf16x8*)&sVt[(jd * 16 + c16) * 132 + ks * 32 + quad * 8];
        o_acc[0][jd] = __builtin_amdgcn_mfma_f32_16x16x32_bf16(ap[0], bv, o_acc[0][jd], 0, 0, 0);
        o_acc[1][jd] = __builtin_amdgcn_mfma_f32_16x16x32_bf16(ap[1], bv, o_acc[1][jd], 0, 0, 0);
      }
    }
  }

  // p_sum: reduce across the 4 quads (each lane then has the full row sum for q=c16)
#pragma unroll
  for (int m = 0; m < 2; m++) {
    p_sum[m] += __shfl_xor(p_sum[m], 16, 64);
    p_sum[m] += __shfl_xor(p_sum[m], 32, 64);
  }

  // epilogue: o_acc D-layout row = q_local = quad*4+r, col = d = c16.
  // Fetch the matching row sum from the lane whose c16 == quad*4+r.
#pragma unroll
  for (int m = 0; m < 2; m++) {
#pragma unroll
    for (int r = 0; r < 4; r++) {
      const float ps = __shfl(p_sum[m], quad * 4 + r, 64);
      const float inv = 1.0f / ps;
      const long rowbase = ((long)b * 2048 + q0 + wave * 32 + m * 16 + quad * 4 + r) * 1024 + h * 64;
#pragma unroll
      for (int jd = 0; jd < 4; jd++)
        att[rowbase + jd * 16 + c16] = (bf16)(o_acc[m][jd][r] * inv);
    }
  }
}

// ---------------- launcher ----------------
extern "C" void kernel_launch(void* const* d_in, const int* in_sizes, int n_in,
                              void* d_out, int out_size, void* d_ws, size_t ws_size,
                              hipStream_t stream) {
  (void)in_sizes; (void)n_in; (void)out_size; (void)ws_size;
  const float* x     = (const float*)d_in[0];
  const float* w_qkv = (const float*)d_in[1];
  const float* b_qkv = (const float*)d_in[2];
  const float* w_out = (const float*)d_in[3];
  const float* b_out = (const float*)d_in[4];
  const float* gamma = (const float*)d_in[5];
  const float* beta  = (const float*)d_in[6];
  float* out = (float*)d_out;
  bf16* ws  = (bf16*)d_ws;

  // ws layout (bf16 elems), total 37.75M elems = 75.5 MB
  bf16* xn    = ws;                    // 8192*1024 (reused as att buffer)
  bf16* wqkvT = ws + 8388608;          // 3072*1024
  bf16* woutT = wqkvT + 3145728;       // 1024*1024
  bf16* qbuf  = woutT + 1048576;       // 8192*1024
  bf16* kbuf  = qbuf + 8388608;        // 8192*1024
  bf16* vtbuf = kbuf + 8388608;        // 8192*1024
  bf16* att   = xn;                    // alias: xn dead after QKV GEMM

  transpose2_kernel<<<dim3(128, 32), 256, 0, stream>>>(w_qkv, wqkvT, w_out, woutT);
  ln_kernel<<<dim3(8192), 256, 0, stream>>>(x, gamma, beta, xn);
  gemm_bt<<<dim3(8192 / 128, 3072 / 128), 256, 0, stream>>>(
      xn, wqkvT, b_qkv, (float*)nullptr, qbuf, kbuf, vtbuf, 1024, 3072, 1);
  attn_kernel<<<dim3(1024), 256, 0, stream>>>(qbuf, kbuf, vtbuf, att);
  gemm_bt<<<dim3(8192 / 128, 1024 / 128), 256, 0, stream>>>(
      att, woutT, b_out, out, (bf16*)nullptr, (bf16*)nullptr, (bf16*)nullptr, 1024, 1024, 0);
}

// Round 6
// 272.545 us; speedup vs baseline: 1.0415x; 1.0415x over previous
//
#include <hip/hip_runtime.h>
#include <stdint.h>

typedef __bf16 bf16;
typedef bf16 bf16x4 __attribute__((ext_vector_type(4)));
typedef bf16 bf16x8 __attribute__((ext_vector_type(8)));
typedef float f32x4 __attribute__((ext_vector_type(4)));

// Inputs fp32, output fp32. Internal: bf16 MFMA, fp32 acc.
// Q is pre-scaled by 0.125*log2(e) in the QKV epilogue so attention softmax
// is exp2(s) with zero extra VALU per element.

// Async global->LDS, 16B/lane; LDS dest = wave-uniform base + lane*16 [m97].
__device__ __forceinline__ void gll16(const bf16* g, const bf16* l) {
  __builtin_amdgcn_global_load_lds(
      (__attribute__((address_space(1))) void*)(g),
      (__attribute__((address_space(3))) void*)(l),
      16, 0, 0);
}

// ---------------- LayerNorm: one block per row of 1024, fp32 in -> bf16 out ----------------
__global__ __launch_bounds__(256) void ln_kernel(
    const float* __restrict__ x, const float* __restrict__ gamma,
    const float* __restrict__ beta, bf16* __restrict__ xn)
{
  __shared__ float red[8];
  const long row = blockIdx.x;
  const int t = threadIdx.x;
  f32x4 f = *(const f32x4*)(x + row * 1024 + t * 4);
  float sum = f[0] + f[1] + f[2] + f[3];
  float sq  = f[0]*f[0] + f[1]*f[1] + f[2]*f[2] + f[3]*f[3];
#pragma unroll
  for (int sh = 1; sh < 64; sh <<= 1) {
    sum += __shfl_xor(sum, sh, 64);
    sq  += __shfl_xor(sq,  sh, 64);
  }
  const int wave = t >> 6, lane = t & 63;
  if (lane == 0) { red[wave] = sum; red[wave + 4] = sq; }
  __syncthreads();
  sum = red[0] + red[1] + red[2] + red[3];
  sq  = red[4] + red[5] + red[6] + red[7];
  const float mu  = sum * (1.0f / 1024.0f);
  const float var = sq * (1.0f / 1024.0f) - mu * mu;
  const float rs  = rsqrtf(var + 1e-5f);
  f32x4 g = *(const f32x4*)(gamma + t * 4);
  f32x4 bb = *(const f32x4*)(beta + t * 4);
  bf16x4 ov;
#pragma unroll
  for (int i = 0; i < 4; i++)
    ov[i] = (bf16)((f[i] - mu) * rs * g[i] + bb[i]);
  *(bf16x4*)(xn + row * 1024 + t * 4) = ov;
}

// ---------------- Weight transposes (both weights, one launch): out[c][r] = (bf16)in[r][c] ----------------
// blockIdx.x < 96: w_qkv (1024x3072); else w_out (1024x1024). R = 1024 for both.
__global__ __launch_bounds__(256) void transpose2_kernel(
    const float* __restrict__ wqkv, bf16* __restrict__ wqkvT,
    const float* __restrict__ wout, bf16* __restrict__ woutT)
{
  __shared__ bf16 tile[32][33];
  const int bx = blockIdx.x;
  const float* in;
  bf16* out;
  int Cc, c0;
  if (bx < 96) { in = wqkv; out = wqkvT; Cc = 3072; c0 = bx * 32; }
  else         { in = wout; out = woutT; Cc = 1024; c0 = (bx - 96) * 32; }
  const int r0 = blockIdx.y * 32;
  const int tx = threadIdx.x & 31, ty = threadIdx.x >> 5;
#pragma unroll
  for (int i = 0; i < 32; i += 8)
    tile[ty + i][tx] = (bf16)in[(long)(r0 + ty + i) * Cc + c0 + tx];
  __syncthreads();
#pragma unroll
  for (int i = 0; i < 32; i += 8)
    out[(long)(c0 + ty + i) * 1024 + r0 + tx] = tile[tx][ty + i];
}

// ---------------- GEMM: C[m][n] = sum_k A[m][k] * BT[n][k] + bias[n] ----------------
// 128x128 tile, BK=32, 4 waves each 64x64, global_load_lds x16.
// Depth-2 pipeline (T4, counted vmcnt): 3 LDS buffers rotate; stage(s+2) is
// issued at step s, then inline-asm s_waitcnt vmcnt(8) (allow stages s+1,s+2
// = 8 glls outstanding; retire stage s) + RAW s_barrier (no vmcnt(0) drain).
// Tail peels to vmcnt(4)/vmcnt(0). Hazards: buf[(s+2)%3]=buf[(s-1)%3], whose
// last reads finished before step s-1's closing barrier (precedes the issue).
// LDS bank-swizzle (rule #21: linear gll dest + pre-swizzled SOURCE + swizzled
// READ): 16B granule g of row r stores global granule g ^ ((r>>1)&3).
// Verified R5: SQ_LDS_BANK_CONFLICT 6.29M -> 0.
// mode 0: store C [M][N] fp32. mode 1: QKV scatter bf16 (q/k [bh][l][64], v->vt [bh][64][l]);
//   Q is additionally scaled by 0.125*log2(e) for the exp2-softmax in attn.
__global__ __launch_bounds__(256, 3) void gemm_bt(
    const bf16* __restrict__ A, const bf16* __restrict__ BT,
    const float* __restrict__ bias, float* __restrict__ C,
    bf16* __restrict__ qb, bf16* __restrict__ kb, bf16* __restrict__ vtb,
    int K, int N, int mode)
{
  __shared__ bf16 sA[3][128 * 32];
  __shared__ bf16 sB[3][128 * 32];
  const int t = threadIdx.x;
  const int lane = t & 63;
  const int wave = t >> 6;
  const int wave_u = __builtin_amdgcn_readfirstlane(wave);
  const int quad = lane >> 4;
  const int c16 = lane & 15;
  const int wm = (wave >> 1) * 64;
  const int wn = (wave & 1) * 64;
  const int m0 = blockIdx.x * 128;
  const int n0 = blockIdx.y * 128;

  f32x4 acc[4][4] = {};

  const int srow = t >> 2;                               // 0..63
  const int scol = (((t & 3) ^ ((t >> 3) & 3)) * 8);     // pre-swizzled source granule
  const bf16* gA = A + (long)(m0 + srow) * K + scol;
  const bf16* gB = BT + (long)(n0 + srow) * K + scol;
  const long rowskip = (long)64 * K;
  const int ksw = (quad ^ ((c16 >> 1) & 3)) * 8;         // swizzled read offset (elems)

  const int S = K >> 5;                                  // number of 32-wide K-steps

  // stage K-step kk (global col kk*32) into buffer b
  auto stage = [&](int b, int kk) {
    const bf16* lA = sA[0] + b * 4096 + wave_u * 512;
    const bf16* lB = sB[0] + b * 4096 + wave_u * 512;
    const int k0 = kk * 32;
    gll16(gA + k0, lA);
    gll16(gA + k0 + rowskip, lA + 2048);
    gll16(gB + k0, lB);
    gll16(gB + k0 + rowskip, lB + 2048);
  };

  // prologue: stage steps 0 and 1 (K >= 64 always here)
  stage(0, 0);
  stage(1, 1);

  int bcur = 0;
  for (int s = 0; s < S; s++) {
    if (s + 2 < S) {
      const int bnx = (bcur >= 1) ? bcur - 1 : 2;        // (s+2) % 3
      stage(bnx, s + 2);
      asm volatile("s_waitcnt vmcnt(8)" ::: "memory");   // retire stage(s); keep s+1,s+2 in flight
    } else if (s + 1 < S) {
      asm volatile("s_waitcnt vmcnt(4)" ::: "memory");   // retire stage(s); keep s+1
    } else {
      asm volatile("s_waitcnt vmcnt(0)" ::: "memory");   // last step
    }
    __builtin_amdgcn_s_barrier();                        // all waves' stage(s) slices visible

    const bf16* cA = sA[0] + bcur * 4096;
    const bf16* cB = sB[0] + bcur * 4096;
    bf16x8 af[4], bfr[4];
#pragma unroll
    for (int i = 0; i < 4; i++)
      af[i] = *(const bf16x8*)(cA + (wm + i * 16 + c16) * 32 + ksw);
#pragma unroll
    for (int j = 0; j < 4; j++)
      bfr[j] = *(const bf16x8*)(cB + (wn + j * 16 + c16) * 32 + ksw);
#pragma unroll
    for (int i = 0; i < 4; i++)
#pragma unroll
      for (int j = 0; j < 4; j++)
        acc[i][j] = __builtin_amdgcn_mfma_f32_16x16x32_bf16(af[i], bfr[j], acc[i][j], 0, 0, 0);

    __builtin_amdgcn_s_barrier();                        // reads of buf[bcur] done before overwrite
    bcur = (bcur == 2) ? 0 : bcur + 1;
  }

  // C/D layout: col = lane&15, row = quad*4 + reg   [verified m89/m91]
#pragma unroll
  for (int i = 0; i < 4; i++) {
    const int mbase = m0 + wm + i * 16 + quad * 4;
#pragma unroll
    for (int j = 0; j < 4; j++) {
      const int n = n0 + wn + j * 16 + c16;
      const float bv = bias[n];
      if (mode == 0) {
#pragma unroll
        for (int r = 0; r < 4; r++)
          C[(long)(mbase + r) * N + n] = acc[i][j][r] + bv;
      } else {
        const int part = n >> 10;       // 0=Q 1=K 2=V
        const int inner = n & 1023;
        const int h = inner >> 6, d = inner & 63;
#pragma unroll
        for (int r = 0; r < 4; r++) {
          const int m = mbase + r;
          const int b = m >> 11, l = m & 2047;
          const long bh = (long)((b << 4) | h);
          const float v = acc[i][j][r] + bv;
          if (part == 0)      qb [(bh * 2048 + l) * 64 + d] = (bf16)(v * 0.18033688f); // 0.125*log2e
          else if (part == 1) kb [(bh * 2048 + l) * 64 + d] = (bf16)v;
          else                vtb[(bh * 64 + d) * 2048 + l] = (bf16)v;
        }
      }
    }
  }
}

// ---------------- Flash attention: swapped QK^T, P in registers, 64 q-rows/wave ----------------
// R6 changes vs R5 (layout machinery unchanged):
//  * 4 m-tiles/wave (64 q-rows), block = 256 q-rows, grid = 8 qt x 64 bh = 512
//    = 2 blocks/CU. Each wave still reads sK/sVt exactly once per kv-tile
//    (32 KB) but now feeds 2x the MFMAs -> per-CU LDS traffic HALVES
//    (R5 counters: VALUBusy 43% > MfmaUtil 34%, LDS at ~ceiling).
//  * p_sum computed on the MATRIX pipe: o_sum[m] = mfma(ap[m], ones, o_sum[m]).
//    B=all-ones => every D column = row-sum of P (layout-independent).
//    Deletes 64 VALU adds/lane/iter and the entire end shuffle-reduce;
//    o_sum[m][r] is already in epilogue layout (row = quad*4+r).
//  * Denominator now sums bf16-rounded P -- consistent with numerator P@V.
// Carried from R3-R5:
//  * Swapped QK^T: z = mfma(K_frag, Q_frag) -> S^T, q = lane column; P stays
//    in registers (no LDS round-trip, no third barrier).
//  * kv-axis permutation sigma(16e+4q+r)=8q+4e+r on BOTH operands: P packs
//    lane-locally; V^T staged pre-permuted (two b64 writes per lane).
//  * XCD-affine: i&7 = XCD; XCD x owns bh [8x,8x+8) -> K/V (512 KB/bh) stays
//    in that XCD's 4 MB L2 across all 8 q-tiles.
//  * K and V register-prefetched one 128-kv tile ahead, issued mid-compute.
__global__ __launch_bounds__(256, 2) void attn_kernel(
    const bf16* __restrict__ q, const bf16* __restrict__ k,
    const bf16* __restrict__ vt, bf16* __restrict__ att)
{
  __shared__ bf16 sK[128 * 68];      // [kv][d], stride 68 (34 words, mod32=2)
  __shared__ bf16 sVt[64 * 132];     // [d][kv-permuted], stride 132 (66 words, mod32=2)

  const int i = blockIdx.x;                 // 0..511
  const int xcd = i & 7;
  const int wi = i >> 3;                    // 0..63
  const int qt = wi & 7;
  const int bh = xcd * 8 + (wi >> 3);
  const int b = bh >> 4, h = bh & 15;
  const int q0 = qt * 256;
  const int t = threadIdx.x;
  const int wave = t >> 6, lane = t & 63;
  const int quad = lane >> 4, c16 = lane & 15;

  const bf16* qp = q + (long)bh * (2048 * 64);
  const bf16* kp = k + (long)bh * (2048 * 64);
  const bf16* vp = vt + (long)bh * (64 * 2048);

  // Q fragments (B-operand): B[q=c16][d=quad*8+..], loop-invariant. 4 m-tiles.
  bf16x8 aq[4][2];
#pragma unroll
  for (int m = 0; m < 4; m++) {
    const bf16* qrow = qp + (long)(q0 + wave * 64 + m * 16 + c16) * 64 + quad * 8;
    aq[m][0] = *(const bf16x8*)(qrow);
    aq[m][1] = *(const bf16x8*)(qrow + 32);
  }

  f32x4 o_acc[4][4] = {};
  f32x4 o_sum[4] = {};
  bf16x8 vones;
#pragma unroll
  for (int z = 0; z < 8; z++) vones[z] = (bf16)1.0f;

  // staging indices
  const int kr = t >> 3;             // K row within 32-row group
  const int kd = (t & 7) * 8;
  const int vr = t >> 4;             // Vt row within 16-row group (0..15)
  const int vc = t & 15;             // 8-kv chunk index (0..15)
  const int vl = vc * 8;             // global kv offset
  // permuted LDS dest: chunk ks=vc>>2, cc=vc&3 -> D0 = ks*32 + 16*(cc&1) + 4*(cc>>1)
  const int vD0 = (vc >> 2) * 32 + (vc & 1) * 16 + ((vc >> 1) & 1) * 4;

  // prefetch tile 0 (K and V) into registers
  bf16x8 kreg[4], vreg[4];
#pragma unroll
  for (int it = 0; it < 4; it++) {
    kreg[it] = *(const bf16x8*)(kp + (long)(it * 32 + kr) * 64 + kd);
    vreg[it] = *(const bf16x8*)(vp + (long)(it * 16 + vr) * 2048 + vl);
  }

  for (int kt = 0; kt < 16; kt++) {
    __syncthreads();   // b1: prev iter's LDS reads done
#pragma unroll
    for (int it = 0; it < 4; it++)
      *(bf16x8*)&sK[(it * 32 + kr) * 68 + kd] = kreg[it];
#pragma unroll
    for (int it = 0; it < 4; it++) {
      const bf16x8 v = vreg[it];
      const bf16x4 lo = __builtin_shufflevector(v, v, 0, 1, 2, 3);
      const bf16x4 hi = __builtin_shufflevector(v, v, 4, 5, 6, 7);
      bf16* d = &sVt[(it * 16 + vr) * 132 + vD0];
      *(bf16x4*)(d)     = lo;   // kv 16e+4q+r with r=0..3  -> slots D0..D0+3
      *(bf16x4*)(d + 8) = hi;   // next q group              -> slots D0+8..D0+11
    }
    __syncthreads();   // b2: tiles visible

    const int kvn = ((kt + 1) & 15) * 128;

#pragma unroll
    for (int ks = 0; ks < 4; ks++) {
      bf16x8 ap[4];
      // QK^T (swapped) + exp2 + lane-local pack for this 32-kv chunk
#pragma unroll
      for (int e = 0; e < 2; e++) {
        const int jb = ks * 2 + e;
        const bf16x8 bk0 = *(const bf16x8*)&sK[(jb * 16 + c16) * 68 + quad * 8];
        const bf16x8 bk1 = *(const bf16x8*)&sK[(jb * 16 + c16) * 68 + 32 + quad * 8];
#pragma unroll
        for (int m = 0; m < 4; m++) {
          f32x4 z = {};
          z = __builtin_amdgcn_mfma_f32_16x16x32_bf16(bk0, aq[m][0], z, 0, 0, 0);
          z = __builtin_amdgcn_mfma_f32_16x16x32_bf16(bk1, aq[m][1], z, 0, 0, 0);
          // D: row = kv_local = quad*4+r, col = q = c16
#pragma unroll
          for (int r = 0; r < 4; r++)
            ap[m][e * 4 + r] = (bf16)__builtin_amdgcn_exp2f(z[r]);  // slot sigma(kv)
        }
      }
      // mid-compute prefetch of next tile (latency hidden under remaining MFMAs)
      if (ks == 1) {
#pragma unroll
        for (int it = 0; it < 4; it++)
          kreg[it] = *(const bf16x8*)(kp + (long)(kvn + it * 32 + kr) * 64 + kd);
      }
      if (ks == 2) {
#pragma unroll
        for (int it = 0; it < 4; it++)
          vreg[it] = *(const bf16x8*)(vp + (long)(it * 16 + vr) * 2048 + kvn + vl);
      }
      // row-sums of P on the matrix pipe (B = ones)
#pragma unroll
      for (int m = 0; m < 4; m++)
        o_sum[m] = __builtin_amdgcn_mfma_f32_16x16x32_bf16(ap[m], vones, o_sum[m], 0, 0, 0);
      // O += P @ V over this 32-kv chunk (V^T pre-permuted: contiguous b128)
#pragma unroll
      for (int jd = 0; jd < 4; jd++) {
        const bf16x8 bv = *(const bf16x8*)&sVt[(jd * 16 + c16) * 132 + ks * 32 + quad * 8];
#pragma unroll
        for (int m = 0; m < 4; m++)
          o_acc[m][jd] = __builtin_amdgcn_mfma_f32_16x16x32_bf16(ap[m], bv, o_acc[m][jd], 0, 0, 0);
      }
    }
  }

  // epilogue: o_acc/o_sum D-layout row = q_local = quad*4+r, col = c16.
  // o_sum's every column holds the row sum -> it is already in epilogue layout.
#pragma unroll
  for (int m = 0; m < 4; m++) {
#pragma unroll
    for (int r = 0; r < 4; r++) {
      const float inv = 1.0f / o_sum[m][r];
      const long rowbase = ((long)b * 2048 + q0 + wave * 64 + m * 16 + quad * 4 + r) * 1024 + h * 64;
#pragma unroll
      for (int jd = 0; jd < 4; jd++)
        att[rowbase + jd * 16 + c16] = (bf16)(o_acc[m][jd][r] * inv);
    }
  }
}

// ---------------- launcher ----------------
extern "C" void kernel_launch(void* const* d_in, const int* in_sizes, int n_in,
                              void* d_out, int out_size, void* d_ws, size_t ws_size,
                              hipStream_t stream) {
  (void)in_sizes; (void)n_in; (void)out_size; (void)ws_size;
  const float* x     = (const float*)d_in[0];
  const float* w_qkv = (const float*)d_in[1];
  const float* b_qkv = (const float*)d_in[2];
  const float* w_out = (const float*)d_in[3];
  const float* b_out = (const float*)d_in[4];
  const float* gamma = (const float*)d_in[5];
  const float* beta  = (const float*)d_in[6];
  float* out = (float*)d_out;
  bf16* ws  = (bf16*)d_ws;

  // ws layout (bf16 elems), total 37.75M elems = 75.5 MB
  bf16* xn    = ws;                    // 8192*1024 (reused as att buffer)
  bf16* wqkvT = ws + 8388608;          // 3072*1024
  bf16* woutT = wqkvT + 3145728;       // 1024*1024
  bf16* qbuf  = woutT + 1048576;       // 8192*1024
  bf16* kbuf  = qbuf + 8388608;        // 8192*1024
  bf16* vtbuf = kbuf + 8388608;        // 8192*1024
  bf16* att   = xn;                    // alias: xn dead after QKV GEMM

  transpose2_kernel<<<dim3(128, 32), 256, 0, stream>>>(w_qkv, wqkvT, w_out, woutT);
  ln_kernel<<<dim3(8192), 256, 0, stream>>>(x, gamma, beta, xn);
  gemm_bt<<<dim3(8192 / 128, 3072 / 128), 256, 0, stream>>>(
      xn, wqkvT, b_qkv, (float*)nullptr, qbuf, kbuf, vtbuf, 1024, 3072, 1);
  attn_kernel<<<dim3(512), 256, 0, stream>>>(qbuf, kbuf, vtbuf, att);
  gemm_bt<<<dim3(8192 / 128, 1024 / 128), 256, 0, stream>>>(
      att, woutT, b_out, out, (bf16*)nullptr, (bf16*)nullptr, (bf16*)nullptr, 1024, 1024, 0);
}